// Round 6
// baseline (141.467 us; speedup 1.0000x reference)
//
#include <hip/hip_runtime.h>
#include <hip/hip_bf16.h>
#include <math.h>

#define N_PTS   2048
#define N_NODES 8192
#define N_CMP   1024
#define CAP     128     // max candidate list length per row
#define K_MIN   32
#define K_MAX   112

// Workspace: bitsT uint[N_NODES*32] @ 0 (1 MiB).
// bitsT layout (ballot-friendly, verified in R4):
//   column c, node n:  g = c>>8, e = c&3, l = (c>>2)&63
//   dword = n*32 + g*8 + e*2 + (l>>5);  bit = l & 31
//   (g*256 + l*4 + e == c)

__device__ __forceinline__ unsigned int float_to_key(float f) {
    unsigned int b = __float_as_uint(f);
    return (b & 0x80000000u) ? ~b : (b | 0x80000000u);
}
__device__ __forceinline__ float key_to_float(unsigned int k) {
    unsigned int b = (k & 0x80000000u) ? (k ^ 0x80000000u) : ~k;
    return __uint_as_float(b);
}
__device__ __forceinline__ int col_word_off(int c) {   // dword offset within node stride 32
    return (c >> 8) * 8 + (c & 3) * 2 + (((c >> 2) & 63) >> 5);
}
__device__ __forceinline__ int col_bit(int c) { return (c >> 2) & 31; }

// ---------------- Kernel 1: bit-pack mask (one wave per (node, 256-col grp)) ----
__global__ __launch_bounds__(256) void pack_kernel(const int4* __restrict__ states4,
                                                   unsigned int* __restrict__ bitsT) {
    int t    = threadIdx.x;
    int lane = t & 63;
    int W = blockIdx.x * 4 + (t >> 6);      // 0 .. 8192*4-1
    int n = W >> 2;
    int g = W & 3;
    int4 v = states4[(size_t)n * 256 + g * 64 + lane];
    unsigned long long b0 = __ballot(v.x != 0);
    unsigned long long b1 = __ballot(v.y != 0);
    unsigned long long b2 = __ballot(v.z != 0);
    unsigned long long b3 = __ballot(v.w != 0);
    if (lane == 0) {
        uint4* dst = reinterpret_cast<uint4*>(bitsT + n * 32 + g * 8);
        dst[0] = make_uint4((unsigned)b0, (unsigned)(b0 >> 32),
                            (unsigned)b1, (unsigned)(b1 >> 32));
        dst[1] = make_uint4((unsigned)b2, (unsigned)(b2 >> 32),
                            (unsigned)b3, (unsigned)(b3 >> 32));
    }
}

// ---------------- Kernel 2: fused select + probe, 1024 threads/block --------
// 2 blocks/CU resident -> 4 generations/CU -> phases overlap across blocks.
__global__ __launch_bounds__(1024) void fused_kernel(const float* __restrict__ x,
                                                     const int* __restrict__ states,
                                                     const unsigned int* __restrict__ bitsT,
                                                     float* __restrict__ out) {
    int p    = blockIdx.x;
    int t    = threadIdx.x;
    int lane = t & 63;
    int w    = t >> 6;                       // wave 0..15

    const float4* row4 = reinterpret_cast<const float4*>(x + (size_t)p * N_NODES);

    // element index of key[j*4+e] is j*4096 + t*4 + e
    unsigned int key[8];
#pragma unroll
    for (int j = 0; j < 2; j++) {
        float4 v = row4[j * 1024 + t];
        key[j * 4 + 0] = float_to_key(v.x);
        key[j * 4 + 1] = float_to_key(v.y);
        key[j * 4 + 2] = float_to_key(v.z);
        key[j * 4 + 3] = float_to_key(v.w);
    }

    __shared__ unsigned int s_cnt[2][16];
    __shared__ unsigned int s_red[16];
    __shared__ unsigned int s_key[CAP];
    __shared__ int          s_id[CAP];
    __shared__ float        s_sv[CAP];       // sorted values (desc)
    __shared__ int          s_sn[CAP];       // sorted node ids
    __shared__ int          s_num;

    // ---- block max of keys ----
    unsigned int m = 0;
#pragma unroll
    for (int i = 0; i < 8; i++) m = max(m, key[i]);
#pragma unroll
    for (int d = 1; d < 64; d <<= 1)
        m = max(m, (unsigned int)__shfl_xor((int)m, d));
    if (lane == 0) s_red[w] = m;
    __syncthreads();
    unsigned int M = 0;
#pragma unroll
    for (int i = 0; i < 16; i++) M = max(M, s_red[i]);
    __syncthreads();

    // ---- bisection: find T with count(key >= T) in [K_MIN, K_MAX] ----
    unsigned int lo = 0, hi = M;
    for (int it = 0; it < 34; ++it) {
        if (hi - lo <= 1) break;
        unsigned int mid;
        if (it == 0) {
            mid = 0xC0200000u;               // key(2.5f): ~51 hits on N(0,1) rows
            if (mid >= hi) mid = hi - 1;
            if (mid <= lo) mid = lo + 1;
        } else {
            mid = lo + ((hi - lo) >> 1);
        }
        int myc = 0;
#pragma unroll
        for (int i = 0; i < 8; i++)
            myc += (int)__popcll(__ballot(key[i] >= mid));
        int par = it & 1;
        if (lane == 0) s_cnt[par][w] = (unsigned int)myc;
        __syncthreads();
        int c = 0;
#pragma unroll
        for (int i = 0; i < 16; i++) c += (int)s_cnt[par][i];
        if (c >= K_MIN) {
            lo = mid;
            if (c <= K_MAX) break;
        } else {
            hi = mid;
        }
    }
    unsigned int T = lo;

    // ---- compact keys >= T into LDS ----
    if (t == 0) s_num = 0;
    __syncthreads();
#pragma unroll
    for (int i = 0; i < 8; i++) {
        if (key[i] >= T) {
            int pos = atomicAdd(&s_num, 1);
            if (pos < CAP) {
                s_key[pos] = key[i];
                s_id[pos]  = (i >> 2) * 4096 + (t << 2) + (i & 3);
            }
        }
    }
    __syncthreads();
    int L   = s_num;
    int len = (L > CAP) ? -1 : L;            // pathological ties -> row fallback

    // ---- rank-sort descending into s_sv / s_sn ----
    if (len > 0 && t < L) {
        unsigned int mk = s_key[t];
        int          mi = s_id[t];
        int r = 0;
        for (int j = 0; j < L; ++j) {
            unsigned int kj = s_key[j];
            r += (int)((kj > mk) | ((kj == mk) & (j < t)));
        }
        s_sv[r] = key_to_float(mk);
        s_sn[r] = mi;
    }
    __syncthreads();

    // ---- probe: wave w handles column-group w exactly ----
    int c    = w * 64 + lane;
    int woff = col_word_off(c);
    int bit  = col_bit(c);

    float res  = 0.0f;
    bool  done = false;

    if (len >= 0) {
#pragma unroll 1
        for (int k0 = 0; k0 < len; k0 += 16) {
            int kmax = len - k0;
            if (kmax > 16) kmax = 16;
            unsigned int wb[16];
#pragma unroll
            for (int j = 0; j < 16; j++)
                if (j < kmax) wb[j] = bitsT[s_sn[k0 + j] * 32 + woff];  // 8B/wave, L2-hit
#pragma unroll
            for (int j = 0; j < 16; j++) {
                if (j < kmax) {
                    bool hit = (wb[j] >> bit) & 1u;
                    if (!done && hit) { res = s_sv[k0 + j]; done = true; }
                }
            }
            if (__all((int)done)) break;
        }
    }

    if (!done) {
        // exact fallback (P(taken) ~ 2^-32 per pair; needed for ties overflow)
        const float* row = x + (size_t)p * N_NODES;
        float mm = -INFINITY;
        for (int n = 0; n < N_NODES; n++) {
            if (states[(size_t)n * N_CMP + c] != 0) mm = fmaxf(mm, row[n]);
        }
        res = (mm == -INFINITY) ? 0.0f : mm;
    }

    out[(size_t)p * N_CMP + c] = res;
}

// ---------------- launch ----------------
extern "C" void kernel_launch(void* const* d_in, const int* in_sizes, int n_in,
                              void* d_out, int out_size, void* d_ws, size_t ws_size,
                              hipStream_t stream) {
    const float* x       = (const float*)d_in[0];
    const int*   states  = (const int*)d_in[1];
    const int4*  states4 = (const int4*)d_in[1];
    float*       out     = (float*)d_out;
    unsigned int* bitsT  = (unsigned int*)d_ws;

    pack_kernel<<<N_NODES * 4 / 4, 256, 0, stream>>>(states4, bitsT);
    fused_kernel<<<N_PTS, 1024, 0, stream>>>(x, states, bitsT, out);
}